// Round 15
// baseline (221.470 us; speedup 1.0000x reference)
//
#include <hip/hip_runtime.h>
#include <hip/hip_bf16.h>

// Problem constants (from reference): B=8, C=16, H=512, W=512, M=15, N=15
#define BC    128          // B*C
#define Hh    512
#define Ww    512
#define P16   16           // M+1
#define Q16   16           // N+1
#define HTILE 64           // h rows per eval block -> grid 8*128 = 1024 = 4 blocks/CU
#define NHT   (Hh / HTILE) // 8 h-tiles

// ---------------------------------------------------------------------------
// Kernel 1: extract separable factors by DIVISION (basis = exact fp32
// products Bu[h,p]*Bv[w,q]):
//   Bu00 = sum_q basis[0,0,q] (partition of unity)
//   Bv[w,q] = basis[w,0,q]/Bu00,  Bu[h,p] = basis[h*W,p,0]/Bv[0,0]
// Bv stored TRANSPOSED (BvT[q][w]) so eval Phase-A loads are lane-contiguous.
// ---------------------------------------------------------------------------
__global__ __launch_bounds__(256)
void extract_factors(const float* __restrict__ basis,
                     float* __restrict__ Bu,
                     float* __restrict__ BvT) {
    float bu00 = 0.f;
    #pragma unroll
    for (int q = 0; q < Q16; ++q) bu00 += basis[q];     // basis[0,0,q], uniform
    const float rinv  = 1.0f / bu00;                    // 1/Bu[0,0]
    const float rinv2 = bu00 / basis[0];                // 1/Bv[0,0]

    int tid = blockIdx.x * 256 + threadIdx.x;           // 0..16383
    if (tid < Hh * P16) {
        int h = tid >> 4, p = tid & 15;
        float v = basis[(size_t)h * Ww * (P16 * Q16) + p * Q16];  // basis[h*W, p, 0]
        Bu[tid] = v * rinv2;                            // Bu[h][p]
    } else {
        int t2 = tid - Hh * P16;
        int w = t2 >> 4, q = t2 & 15;
        float v = basis[(size_t)w * (P16 * Q16) + q];   // basis[w, 0, q]
        BvT[(size_t)q * Ww + w] = v * rinv;             // TRANSPOSED
    }
}

// ---------------------------------------------------------------------------
// Kernel 2 — LDS-shared T, w-quad Phase B, contiguous 1 KB wave stores.
//   waves_per_eu(4,4): pin 4 waves/SIMD (128-VGPR budget) — measured
//   occupancy dose-response: 2w=68us, 4w=35.9us, 8w(strangled)=41.5us.
//   Phase A (all 256 threads): tq=t&127 owns w-quad 4tq; ph=(t>>7)*8 owns
//     8 of 16 p. 512 FMA/thread (same as R9), Ts[p][w] via ds_write_b128.
//   Phase B: t&127 -> w-quad, t>>7 -> 32-row h-half. 16x ds_read_b128
//     (conflict-free contiguous pattern), then per row: 16 uniform scalar
//     Bu loads + 64 FMA + ONE b128 store; wave store = 1 KB single row
//     (fill-kernel parity). No shuffles anywhere.
// ---------------------------------------------------------------------------
__global__ __launch_bounds__(256)
__attribute__((amdgpu_waves_per_eu(4, 4)))
void bezier_eval(const float* __restrict__ K,
                 const float* __restrict__ Bu,
                 const float* __restrict__ BvT,
                 float* __restrict__ out) {
    __shared__ float Ts[P16][Ww];        // 32 KiB -> 4 blocks/CU = 128 KiB
    const int t     = threadIdx.x;       // 0..255
    const int htile = blockIdx.x;        // 0..7
    const int bc    = blockIdx.y;        // 0..127

    const float* __restrict__ Kp = K + (size_t)bc * (P16 * Q16);  // uniform

    // ---- Phase A: half the p-range per thread, w-quad 4*(t&127) ----
    {
        const int tq = t & 127;
        const int ph = (t >> 7) * 8;               // p offset 0 or 8
        const int w0 = 4 * tq;

        float4 A0 = make_float4(0,0,0,0), A1 = make_float4(0,0,0,0);
        float4 A2 = make_float4(0,0,0,0), A3 = make_float4(0,0,0,0);
        float4 A4 = make_float4(0,0,0,0), A5 = make_float4(0,0,0,0);
        float4 A6 = make_float4(0,0,0,0), A7 = make_float4(0,0,0,0);

        #pragma unroll
        for (int qb = 0; qb < 4; ++qb) {           // 4 q at a time: bv live = 16 regs
            const float* bvq = BvT + (size_t)(qb * 4) * Ww + w0;
            float4 v0 = *(const float4*)(bvq + 0 * Ww);   // coalesced 1 KB/wave
            float4 v1 = *(const float4*)(bvq + 1 * Ww);
            float4 v2 = *(const float4*)(bvq + 2 * Ww);
            float4 v3 = *(const float4*)(bvq + 3 * Ww);
            #define PA(Ap, pofs) { \
                const float* kq = Kp + (ph + (pofs)) * Q16 + qb * 4;  /* uniform */ \
                float k0 = kq[0], k1 = kq[1], k2 = kq[2], k3 = kq[3]; \
                Ap.x = fmaf(k0, v0.x, Ap.x); Ap.y = fmaf(k0, v0.y, Ap.y); \
                Ap.z = fmaf(k0, v0.z, Ap.z); Ap.w = fmaf(k0, v0.w, Ap.w); \
                Ap.x = fmaf(k1, v1.x, Ap.x); Ap.y = fmaf(k1, v1.y, Ap.y); \
                Ap.z = fmaf(k1, v1.z, Ap.z); Ap.w = fmaf(k1, v1.w, Ap.w); \
                Ap.x = fmaf(k2, v2.x, Ap.x); Ap.y = fmaf(k2, v2.y, Ap.y); \
                Ap.z = fmaf(k2, v2.z, Ap.z); Ap.w = fmaf(k2, v2.w, Ap.w); \
                Ap.x = fmaf(k3, v3.x, Ap.x); Ap.y = fmaf(k3, v3.y, Ap.y); \
                Ap.z = fmaf(k3, v3.z, Ap.z); Ap.w = fmaf(k3, v3.w, Ap.w); }
            PA(A0,0) PA(A1,1) PA(A2,2) PA(A3,3)
            PA(A4,4) PA(A5,5) PA(A6,6) PA(A7,7)
            #undef PA
        }
        // conflict-free contiguous ds_write_b128 (lanes cover w 0..255/256..511)
        *(float4*)&Ts[ph + 0][w0] = A0;
        *(float4*)&Ts[ph + 1][w0] = A1;
        *(float4*)&Ts[ph + 2][w0] = A2;
        *(float4*)&Ts[ph + 3][w0] = A3;
        *(float4*)&Ts[ph + 4][w0] = A4;
        *(float4*)&Ts[ph + 5][w0] = A5;
        *(float4*)&Ts[ph + 6][w0] = A6;
        *(float4*)&Ts[ph + 7][w0] = A7;
    }
    __syncthreads();

    // ---- Phase B: w-quad + 32-row h-half per thread ----
    const int w0 = 4 * (t & 127);
    const int hq = t >> 7;               // 0 or 1

    float4 T0  = *(const float4*)&Ts[ 0][w0];
    float4 T1  = *(const float4*)&Ts[ 1][w0];
    float4 T2  = *(const float4*)&Ts[ 2][w0];
    float4 T3  = *(const float4*)&Ts[ 3][w0];
    float4 T4  = *(const float4*)&Ts[ 4][w0];
    float4 T5  = *(const float4*)&Ts[ 5][w0];
    float4 T6  = *(const float4*)&Ts[ 6][w0];
    float4 T7  = *(const float4*)&Ts[ 7][w0];
    float4 T8  = *(const float4*)&Ts[ 8][w0];
    float4 T9  = *(const float4*)&Ts[ 9][w0];
    float4 T10 = *(const float4*)&Ts[10][w0];
    float4 T11 = *(const float4*)&Ts[11][w0];
    float4 T12 = *(const float4*)&Ts[12][w0];
    float4 T13 = *(const float4*)&Ts[13][w0];
    float4 T14 = *(const float4*)&Ts[14][w0];
    float4 T15 = *(const float4*)&Ts[15][w0];

    const int hbase = htile * HTILE + hq * 32;
    const float* __restrict__ bu = Bu + (size_t)hbase * P16;      // uniform
    float* __restrict__ outp = out + ((size_t)bc * Hh + hbase) * Ww + w0;

    #pragma unroll 4
    for (int h = 0; h < 32; ++h) {
        const float* br = bu + h * P16;            // uniform -> scalar loads
        float4 acc = make_float4(0.f, 0.f, 0.f, 0.f);
        #define PB(Tp, pidx) { \
            float b = br[pidx]; \
            acc.x = fmaf(b, Tp.x, acc.x); acc.y = fmaf(b, Tp.y, acc.y); \
            acc.z = fmaf(b, Tp.z, acc.z); acc.w = fmaf(b, Tp.w, acc.w); }
        PB(T0,0)  PB(T1,1)  PB(T2,2)  PB(T3,3)
        PB(T4,4)  PB(T5,5)  PB(T6,6)  PB(T7,7)
        PB(T8,8)  PB(T9,9)  PB(T10,10) PB(T11,11)
        PB(T12,12) PB(T13,13) PB(T14,14) PB(T15,15)
        #undef PB
        *(float4*)(outp + (size_t)h * Ww) = acc;   // 1 KB contiguous per wave
    }
}

extern "C" void kernel_launch(void* const* d_in, const int* in_sizes, int n_in,
                              void* d_out, int out_size, void* d_ws, size_t ws_size,
                              hipStream_t stream) {
    const float* K     = (const float*)d_in[0];   // [128, 16, 16]
    const float* basis = (const float*)d_in[1];   // [262144, 16, 16]
    float* out = (float*)d_out;                   // [128, 512, 512]

    float* Bu  = (float*)d_ws;                    // [512][16]  (32 KiB)
    float* BvT = Bu + Hh * P16;                   // [16][512]  (32 KiB, transposed)

    extract_factors<<<64, 256, 0, stream>>>(basis, Bu, BvT);

    dim3 grid(NHT, BC);                           // 1024 blocks = 4/CU, one round
    bezier_eval<<<grid, 256, 0, stream>>>(K, Bu, BvT, out);
}

// Round 16
// 36.480 us; speedup vs baseline: 6.0710x; 6.0710x over previous
//
#include <hip/hip_runtime.h>
#include <hip/hip_bf16.h>

// Problem constants (from reference): B=8, C=16, H=512, W=512, M=15, N=15
#define BC    128          // B*C
#define Hh    512
#define Ww    512
#define P16   16           // M+1
#define Q16   16           // N+1
#define HTILE 64           // h rows per eval block -> grid 8*128 = 1024 = 4 blocks/CU
#define NHT   (Hh / HTILE) // 8 h-tiles

typedef float v2f __attribute__((ext_vector_type(2)));

static __device__ __forceinline__ v2f pkfma(v2f a, v2f b, v2f c) {
    return __builtin_elementwise_fma(a, b, c);   // -> v_pk_fma_f32 (VOP3P)
}

// ---------------------------------------------------------------------------
// Kernel 1: extract separable factors by DIVISION (identical to R12):
//   Bu00 = sum_q basis[0,0,q];  Bv[w,q] = basis[w,0,q]/Bu00;
//   Bu[h,p] = basis[h*W,p,0]/Bv[0,0]
// Row-major compact tables (R11: reading from basis inside eval = 2.7x loss).
// ---------------------------------------------------------------------------
__global__ __launch_bounds__(256)
void extract_factors(const float* __restrict__ basis,
                     float* __restrict__ Bu,
                     float* __restrict__ Bv) {
    float bu00 = 0.f;
    #pragma unroll
    for (int q = 0; q < Q16; ++q) bu00 += basis[q];     // basis[0,0,q], uniform
    const float rinv  = 1.0f / bu00;                    // 1/Bu[0,0]
    const float rinv2 = bu00 / basis[0];                // 1/Bv[0,0]

    int tid = blockIdx.x * 256 + threadIdx.x;           // 0..16383
    if (tid < Hh * P16) {
        int h = tid >> 4, p = tid & 15;
        float v = basis[(size_t)h * Ww * (P16 * Q16) + p * Q16];  // basis[h*W, p, 0]
        Bu[tid] = v * rinv2;
    } else {
        int t2 = tid - Hh * P16;
        float v = basis[(size_t)(t2 >> 4) * (P16 * Q16) + (t2 & 15)];  // basis[w, 0, q]
        Bv[t2] = v * rinv;
    }
}

// ---------------------------------------------------------------------------
// Kernel 2 — R12 structure (w-pair/thread, HTILE=64, lb(256,4), b128
// lane-pair stores) with PACKED-FP32 math (v_pk_fma_f32, 2 FMA/instr).
// No-splat packing: the packed axis is always a reduction axis whose
// operand pairs are contiguous in memory (SGPR-pair uniform loads) or
// pre-packed VGPR pairs:
//   Phase A: pack q-pairs.  T_row[p] = sum_j pk( K[p][2j:2j+1], bv[2j:2j+1] )
//            -> horizontal add -> packed into Tx/Ty by p-pair:
//            Tx[pp] = {T(2pp) row2t,  T(2pp+1) row2t},  Ty = row 2t+1.
//   Phase B: pack p-pairs.  out = sum_pp pk( Bu[h][2pp:2pp+1], Tx/Ty[pp] )
//            -> horizontal add. 32 pk_fma per h-pair vs 64 fma before.
// Live set ~55 regs (Tx/Ty 32 + chunked bv 16 + accs) — under the 64 wall.
// ---------------------------------------------------------------------------
__global__ __launch_bounds__(256, 4)
void bezier_eval(const float* __restrict__ K,
                 const float* __restrict__ Bu,
                 const float* __restrict__ Bv,
                 float* __restrict__ out) {
    const int t     = threadIdx.x;       // 0..255
    const int htile = blockIdx.x;        // 0..7
    const int bc    = blockIdx.y;        // 0..127

    const float* __restrict__ Kp = K + (size_t)bc * (P16 * Q16);  // uniform

    // Bv rows 2t and 2t+1 are contiguous: row 2t+1 = b0 + 8 v2f pairs.
    const v2f* __restrict__ b0 = (const v2f*)(Bv + (size_t)(2 * t) * Q16);
    const v2f* __restrict__ b1 = b0 + 8;

    v2f Tx[8], Ty[8];   // Tx[pp] = {T[2pp].x, T[2pp+1].x} (row 2t), Ty = row 2t+1

    // ---- Phase A: q packed in pairs; 2 chunks of 4 q-pairs (low pressure) ----
    #pragma unroll
    for (int c = 0; c < 2; ++c) {
        v2f r0[4], r1[4];
        #pragma unroll
        for (int j = 0; j < 4; ++j) { r0[j] = b0[4 * c + j]; r1[j] = b1[4 * c + j]; }
        #pragma unroll
        for (int p = 0; p < P16; ++p) {
            const v2f* k2 = (const v2f*)(Kp + p * Q16 + 8 * c);   // uniform SGPR pairs
            v2f aA = {0.f, 0.f}, aB = {0.f, 0.f};
            #pragma unroll
            for (int j = 0; j < 4; ++j) {
                aA = pkfma(k2[j], r0[j], aA);
                aB = pkfma(k2[j], r1[j], aB);
            }
            float sA = aA.x + aA.y;         // horizontal add: dot over this q-chunk
            float sB = aB.x + aB.y;
            if (c == 0) {
                if ((p & 1) == 0) { Tx[p >> 1].x = sA; Ty[p >> 1].x = sB; }
                else              { Tx[p >> 1].y = sA; Ty[p >> 1].y = sB; }
            } else {
                if ((p & 1) == 0) { Tx[p >> 1].x += sA; Ty[p >> 1].x += sB; }
                else              { Tx[p >> 1].y += sA; Ty[p >> 1].y += sB; }
            }
        }
    }

    // ---- Phase B: p packed in pairs; h in pairs; b128 lane-pair stores ----
    const float* __restrict__ bu = Bu + (size_t)htile * (HTILE * P16);
    float* __restrict__ outbase =
        out + ((size_t)bc * Hh + (size_t)htile * HTILE) * Ww + 2 * t;

    const bool odd = (t & 1);
    const int wofs = odd ? -2 : 0;

    #pragma unroll 4
    for (int h = 0; h < HTILE; h += 2) {
        const v2f* bu0 = (const v2f*)(bu + h * P16);        // uniform SGPR pairs
        const v2f* bu1 = (const v2f*)(bu + h * P16 + P16);
        v2f aX0 = {0.f, 0.f}, aY0 = {0.f, 0.f};   // row h:   w0, w0+1
        v2f aX1 = {0.f, 0.f}, aY1 = {0.f, 0.f};   // row h+1: w0, w0+1
        #pragma unroll
        for (int pp = 0; pp < 8; ++pp) {
            v2f k0 = bu0[pp];
            v2f k1 = bu1[pp];
            aX0 = pkfma(k0, Tx[pp], aX0);
            aY0 = pkfma(k0, Ty[pp], aY0);
            aX1 = pkfma(k1, Tx[pp], aX1);
            aY1 = pkfma(k1, Ty[pp], aY1);
        }
        float ax = aX0.x + aX0.y;   // row h,   w0
        float ay = aY0.x + aY0.y;   // row h,   w0+1
        float bx = aX1.x + aX1.y;   // row h+1, w0
        float by = aY1.x + aY1.y;   // row h+1, w0+1

        // lane-pair exchange (R12-identical): even lane emits row h float4,
        // odd lane emits row h+1 float4 at w0-2.
        float sx = __shfl_xor(ax, 1);
        float sy = __shfl_xor(ay, 1);
        float ux = __shfl_xor(bx, 1);
        float uy = __shfl_xor(by, 1);
        float4 v = odd ? make_float4(ux, uy, bx, by)
                       : make_float4(ax, ay, sx, sy);
        const int hrow = h + (odd ? 1 : 0);
        *(float4*)(outbase + (size_t)hrow * Ww + wofs) = v;  // global_store_dwordx4
    }
}

extern "C" void kernel_launch(void* const* d_in, const int* in_sizes, int n_in,
                              void* d_out, int out_size, void* d_ws, size_t ws_size,
                              hipStream_t stream) {
    const float* K     = (const float*)d_in[0];   // [128, 16, 16]
    const float* basis = (const float*)d_in[1];   // [262144, 16, 16]
    float* out = (float*)d_out;                   // [128, 512, 512]

    float* Bu = (float*)d_ws;                     // [512][16]  (32 KiB)
    float* Bv = Bu + Hh * P16;                    // [512][16]  (32 KiB)

    extract_factors<<<64, 256, 0, stream>>>(basis, Bu, Bv);

    dim3 grid(NHT, BC);                           // 1024 blocks = 4/CU, one round
    bezier_eval<<<grid, 256, 0, stream>>>(K, Bu, Bv, out);
}

// Round 17
// 35.952 us; speedup vs baseline: 6.1601x; 1.0147x over previous
//
#include <hip/hip_runtime.h>
#include <hip/hip_bf16.h>

// Problem constants (from reference): B=8, C=16, H=512, W=512, M=15, N=15
#define BC    128          // B*C
#define Hh    512
#define Ww    512
#define P16   16           // M+1
#define Q16   16           // N+1
#define HTILE 64           // h rows per eval block -> grid 8*128 = 1024 = 4 blocks/CU
#define NHT   (Hh / HTILE) // 8 h-tiles

// ---------------------------------------------------------------------------
// FINAL (R12 config, twice-validated 35.9 us):
// Kernel 1: extract separable factors by DIVISION (basis entries are exact
// fp32 products Bu[h,p]*Bv[w,q]):
//   Bu00    = sum_q basis[0,0,q]            (partition of unity: = Bu[0,0])
//   Bv[w,q] = basis[w, 0, q]   / Bu00
//   Bu[h,p] = basis[h*W, p, 0] / Bv[0,0],  Bv[0,0] = basis[0]/Bu00
// Compact 32 KiB staging tables (R11: reading factors straight from basis
// inside eval is a 2.7x regression — the compact tables are load-bearing).
// ---------------------------------------------------------------------------
__global__ __launch_bounds__(256)
void extract_factors(const float* __restrict__ basis,
                     float* __restrict__ Bu,
                     float* __restrict__ Bv) {
    float bu00 = 0.f;
    #pragma unroll
    for (int q = 0; q < Q16; ++q) bu00 += basis[q];     // basis[0,0,q], uniform
    const float rinv  = 1.0f / bu00;                    // 1/Bu[0,0]
    const float rinv2 = bu00 / basis[0];                // 1/Bv[0,0]

    int tid = blockIdx.x * 256 + threadIdx.x;           // 0..16383
    if (tid < Hh * P16) {
        int h = tid >> 4, p = tid & 15;
        float v = basis[(size_t)h * Ww * (P16 * Q16) + p * Q16];  // basis[h*W, p, 0]
        Bu[tid] = v * rinv2;
    } else {
        int t2 = tid - Hh * P16;                        // (w,q) flat
        float v = basis[(size_t)(t2 >> 4) * (P16 * Q16) + (t2 & 15)];  // basis[w, 0, q]
        Bv[t2] = v * rinv;
    }
}

// ---------------------------------------------------------------------------
// Kernel 2 — register-resident, zero LDS, zero barriers; thread t owns
// w-pair 2t,2t+1 and all 64 h rows. Phase A: T[p] = sum_q K[p,q]*Bv[w,q]
// (16 x float2 = 32 VGPRs — fits the compiler's hard 64-VGPR budget, the
// binding constraint of this kernel; any 16-float4 design spills).
// Phase B: h in pairs, lane-pair __shfl_xor repack -> REGULAR b128 stores.
// A/B history: b64 reg 38.8 | b64 NT 39.9 | b128 reg 35.9 | b128 NT 39.5;
// occupancy 2w=68, 4w=35.9, 8w=41.5; pk_fma 36.5; fusion 95; 3-kernel 49.
// ---------------------------------------------------------------------------
__global__ __launch_bounds__(256, 4)
void bezier_eval(const float* __restrict__ K,
                 const float* __restrict__ Bu,
                 const float* __restrict__ Bv,
                 float* __restrict__ out) {
    const int t     = threadIdx.x;       // 0..255
    const int htile = blockIdx.x;        // 0..7
    const int bc    = blockIdx.y;        // 0..127

    const float* __restrict__ Kp = K + (size_t)bc * (P16 * Q16);  // uniform

    // ---- Phase A: build T[p] = (T[p][2t], T[p][2t+1]) ----
    float2 T[P16];
    #pragma unroll
    for (int p = 0; p < P16; ++p) T[p] = make_float2(0.f, 0.f);

    const float4* bvv = (const float4*)(Bv + (size_t)(2 * t) * Q16);

    #pragma unroll
    for (int qb = 0; qb < 2; ++qb) {               // q in blocks of 8
        float4 r00 = bvv[qb * 2 + 0], r01 = bvv[qb * 2 + 1];         // row 2t
        float4 r10 = bvv[4 + qb * 2 + 0], r11 = bvv[4 + qb * 2 + 1]; // row 2t+1
        #pragma unroll
        for (int p = 0; p < P16; ++p) {
            const float* kq = Kp + p * Q16 + qb * 8;   // uniform -> scalar loads
            float2 s = T[p];
            s.x = fmaf(kq[0], r00.x, s.x);  s.y = fmaf(kq[0], r10.x, s.y);
            s.x = fmaf(kq[1], r00.y, s.x);  s.y = fmaf(kq[1], r10.y, s.y);
            s.x = fmaf(kq[2], r00.z, s.x);  s.y = fmaf(kq[2], r10.z, s.y);
            s.x = fmaf(kq[3], r00.w, s.x);  s.y = fmaf(kq[3], r10.w, s.y);
            s.x = fmaf(kq[4], r01.x, s.x);  s.y = fmaf(kq[4], r11.x, s.y);
            s.x = fmaf(kq[5], r01.y, s.x);  s.y = fmaf(kq[5], r11.y, s.y);
            s.x = fmaf(kq[6], r01.z, s.x);  s.y = fmaf(kq[6], r11.z, s.y);
            s.x = fmaf(kq[7], r01.w, s.x);  s.y = fmaf(kq[7], r11.w, s.y);
            T[p] = s;
        }
    }

    // ---- Phase B: 64 rows in pairs; regular b128 stores via lane-pair repack
    const float* __restrict__ bu = Bu + (size_t)htile * (HTILE * P16);
    float* __restrict__ outbase =
        out + ((size_t)bc * Hh + (size_t)htile * HTILE) * Ww + 2 * t;

    const bool odd = (t & 1);
    const int wofs = odd ? -2 : 0;

    #pragma unroll 4
    for (int h = 0; h < HTILE; h += 2) {
        const float* br0 = bu + h * P16;           // uniform -> scalar loads (4 KB table)
        const float* br1 = br0 + P16;
        float ax = 0.f, ay = 0.f, bx = 0.f, by = 0.f;
        #pragma unroll
        for (int p = 0; p < P16; ++p) {
            float c0 = br0[p], c1 = br1[p];
            ax = fmaf(c0, T[p].x, ax);
            ay = fmaf(c0, T[p].y, ay);
            bx = fmaf(c1, T[p].x, bx);
            by = fmaf(c1, T[p].y, by);
        }
        // lane-pair exchange: even lane emits row h (w=2t..2t+3),
        // odd lane emits row h+1 (w=2t-2..2t+1)
        float sx = __shfl_xor(ax, 1);
        float sy = __shfl_xor(ay, 1);
        float ux = __shfl_xor(bx, 1);
        float uy = __shfl_xor(by, 1);
        float4 v = odd ? make_float4(ux, uy, bx, by)
                       : make_float4(ax, ay, sx, sy);
        const int hrow = h + (odd ? 1 : 0);
        *(float4*)(outbase + (size_t)hrow * Ww + wofs) = v;  // global_store_dwordx4
    }
}

extern "C" void kernel_launch(void* const* d_in, const int* in_sizes, int n_in,
                              void* d_out, int out_size, void* d_ws, size_t ws_size,
                              hipStream_t stream) {
    const float* K     = (const float*)d_in[0];   // [128, 16, 16]
    const float* basis = (const float*)d_in[1];   // [262144, 16, 16]
    float* out = (float*)d_out;                   // [128, 512, 512]

    float* Bu = (float*)d_ws;                     // [512][16]  (32 KiB)
    float* Bv = Bu + Hh * P16;                    // [512][16]  (32 KiB)

    extract_factors<<<64, 256, 0, stream>>>(basis, Bu, Bv);

    dim3 grid(NHT, BC);                           // 1024 blocks = 4/CU, one round
    bezier_eval<<<grid, 256, 0, stream>>>(K, Bu, Bv, out);
}